// Round 9
// baseline (502.304 us; speedup 1.0000x reference)
//
#include <hip/hip_runtime.h>

#define N_NODES 50000
#define F_IN 500
#define F_HID 128
#define F_OUT 16
#define NSCAN_BLKS ((N_NODES + 255) / 256)   // 196

// ---------------- bf16 helpers (RTNE pack, shift decode) ----------------

__device__ __forceinline__ unsigned bf16_pack2(float a, float b) {
    unsigned ua = __float_as_uint(a);
    unsigned ub = __float_as_uint(b);
    ua = (ua + 0x7fffu + ((ua >> 16) & 1u)) >> 16;
    ub = (ub + 0x7fffu + ((ub >> 16) & 1u)) >> 16;
    return ua | (ub << 16);
}
__device__ __forceinline__ float bf_lo(unsigned v) { return __uint_as_float(v << 16); }
__device__ __forceinline__ float bf_hi(unsigned v) { return __uint_as_float(v & 0xffff0000u); }

__device__ __forceinline__ unsigned bf16_rtne(float a) {
    unsigned u = __float_as_uint(a);
    return (u + 0x7fffu + ((u >> 16) & 1u)) >> 16;
}

// ---------------- CSR build: count-only hist + cursor reorder, 4 edges/thread ----
// Round-8 analysis: hist_rank + reorder were latency/atomic-bound at ~1 memory op
// per thread (~120-160 us combined, invisible under fused2's 82 in top-5).
// New: (1) no rank array (saves 12.8 MB r+w); placement via cursor atomics
// (cursor init'd to rowptr in finalize); (2) int4 loads, 4 independent
// atomics in flight per thread. Within-node order was already nondeterministic.

__global__ __launch_bounds__(256) void k_hist4(const int* __restrict__ dst,
                                               int* __restrict__ hist, int E) {
    const int base = (blockIdx.x * 256 + threadIdx.x) << 2;
    if (base + 4 <= E) {
        const int4 d = *(const int4*)(dst + base);
        atomicAdd(&hist[d.x], 1);
        atomicAdd(&hist[d.y], 1);
        atomicAdd(&hist[d.z], 1);
        atomicAdd(&hist[d.w], 1);
    } else {
        for (int i = base; i < E; ++i) atomicAdd(&hist[dst[i]], 1);
    }
}

__global__ __launch_bounds__(256) void k_scan_local(const int* __restrict__ hist,
                                                    int* __restrict__ rowptr,
                                                    int* __restrict__ blksum) {
    __shared__ int s[256];
    const int tid = threadIdx.x;
    const int i = blockIdx.x * 256 + tid;
    int v = (i < N_NODES) ? hist[i] : 0;
    s[tid] = v;
    __syncthreads();
#pragma unroll
    for (int ofs = 1; ofs < 256; ofs <<= 1) {
        int t = (tid >= ofs) ? s[tid - ofs] : 0;
        __syncthreads();
        if (tid >= ofs) s[tid] += t;
        __syncthreads();
    }
    if (i < N_NODES) rowptr[i] = s[tid] - v;
    if (tid == 255) blksum[blockIdx.x] = s[255];
}

__global__ __launch_bounds__(256) void k_scan_blk(int* __restrict__ blksum) {
    __shared__ int s[256];
    const int tid = threadIdx.x;
    int v = (tid < NSCAN_BLKS) ? blksum[tid] : 0;
    s[tid] = v;
    __syncthreads();
#pragma unroll
    for (int ofs = 1; ofs < 256; ofs <<= 1) {
        int t = (tid >= ofs) ? s[tid - ofs] : 0;
        __syncthreads();
        if (tid >= ofs) s[tid] += t;
        __syncthreads();
    }
    if (tid < NSCAN_BLKS) blksum[tid] = s[tid] - v;
}

__global__ void k_finalize(const int* __restrict__ hist, int* __restrict__ rowptr,
                           const int* __restrict__ blksum, float* __restrict__ isd,
                           int* __restrict__ cursor, int E) {
    int i = blockIdx.x * 256 + threadIdx.x;
    if (i < N_NODES) {
        const int rp = rowptr[i] + blksum[i >> 8];
        rowptr[i] = rp;
        cursor[i] = rp;
        isd[i] = rsqrtf((float)(hist[i] + 1));  // +1 self-loop
    }
    if (i == 0) rowptr[N_NODES] = E;
}

__global__ __launch_bounds__(256) void k_reorder4(const int* __restrict__ src,
                                                  const int* __restrict__ dst,
                                                  int* __restrict__ cursor,
                                                  int* __restrict__ csr_src, int E) {
    const int base = (blockIdx.x * 256 + threadIdx.x) << 2;
    if (base + 4 <= E) {
        const int4 d = *(const int4*)(dst + base);
        const int4 s = *(const int4*)(src + base);
        const int p0 = atomicAdd(&cursor[d.x], 1);
        const int p1 = atomicAdd(&cursor[d.y], 1);
        const int p2 = atomicAdd(&cursor[d.z], 1);
        const int p3 = atomicAdd(&cursor[d.w], 1);
        csr_src[p0] = s.x;
        csr_src[p1] = s.y;
        csr_src[p2] = s.z;
        csr_src[p3] = s.w;
    } else {
        for (int i = base; i < E; ++i) {
            const int p = atomicAdd(&cursor[dst[i]], 1);
            csr_src[p] = src[i];
        }
    }
}

// ---------------- Wc = Wlin @ W2  [16,128] ----------------

__global__ void k_wc(const float* __restrict__ W2, const float* __restrict__ Wlin,
                     float* __restrict__ Wc) {
    const int c = blockIdx.x;       // 0..15
    const int j = threadIdx.x;      // 0..127
    const float* wl = Wlin + c * 128;
    float acc = 0.f;
#pragma unroll 4
    for (int k = 0; k < 128; ++k) acc += wl[k] * W2[k * 128 + j];
    Wc[c * 128 + j] = acc;
}

// ---------------- W1 pack: fragment-major bf16 hi/lo, padded K 500->512 ----------------

__global__ __launch_bounds__(256) void k_w1pack(const float* __restrict__ W1,
                                                ushort* __restrict__ wpk) {
    int t = blockIdx.x * 256 + threadIdx.x;   // (kt*8+f)*64 + lane ; 8192 total
    if (t >= 8192) return;
    const int lane = t & 63;
    const int fkt = t >> 6;
    const int f = fkt & 7;
    const int kt = fkt >> 3;
    const int n = (f << 4) + (lane & 15);
    const int kb = (kt << 5) + ((lane >> 4) << 3);
    ushort h8[8], l8[8];
#pragma unroll
    for (int j = 0; j < 8; ++j) {
        const int k = kb + j;
        float v = (k < F_IN) ? W1[n * F_IN + k] : 0.f;
        unsigned h = bf16_rtne(v);
        float fh = __uint_as_float(h << 16);
        unsigned l = bf16_rtne(v - fh);      // Dekker residual, exact in fp32
        h8[j] = (ushort)h;
        l8[j] = (ushort)l;
    }
    const size_t base = ((size_t)fkt << 10);         // (kt*8+f)*1024 elements
    *(uint4*)(wpk + base + (lane << 3))       = *(const uint4*)h8;
    *(uint4*)(wpk + base + 512 + (lane << 3)) = *(const uint4*)l8;
}

// ---------------- GEMM1 via MFMA + glds-staged B: g[M,128](bf16) = isd * (A @ W1^T) ----
// (round-4/5 proven) 3-pass Dekker split; glds w=16; dbuf; one barrier/kt.

typedef __attribute__((ext_vector_type(8))) short s16x8;
typedef __attribute__((ext_vector_type(4))) float f32x4;

typedef const __attribute__((address_space(1))) unsigned u32_glb;
typedef __attribute__((address_space(3))) unsigned u32_lds;

__device__ __forceinline__ void glds16(const void* g, void* l) {
    __builtin_amdgcn_global_load_lds((u32_glb*)g, (u32_lds*)l, 16, 0, 0);
}

__global__ __launch_bounds__(256) void gemm1_mfma5(const float* __restrict__ A,
                                                   const ushort* __restrict__ wpk,
                                                   const float* __restrict__ isd,
                                                   unsigned* __restrict__ hb, int M) {
    __shared__ __align__(16) ushort Bs[2][8192];   // 2 x 16 KB

    const int tid = threadIdx.x;
    const int lane = tid & 63;
    const int wave = tid >> 6;                // 0..3
    const int jcol = lane & 15;
    const int kgrp = lane >> 4;
    const int klo  = kgrp << 3;

    const int m0  = blockIdx.x * 64 + wave * 16;
    const int arw = m0 + jcol;
    const float* arow = A + (size_t)((arw < M) ? arw : (M - 1)) * F_IN;

#define ISSUE_TILE(KT, B)                                                        \
    {                                                                            \
        const ushort* tb_ = wpk + ((size_t)(KT) << 13);                          \
        _Pragma("unroll") for (int c_ = 0; c_ < 4; ++c_) {                       \
            glds16(tb_ + ((c_ * 256 + wave * 64 + lane) << 3),                   \
                   &Bs[B][(c_ * 256 + wave * 64) << 3]);                         \
        }                                                                        \
    }

    const float4 zf4 = make_float4(0.f, 0.f, 0.f, 0.f);
    float4 ca0 = zf4, ca1 = zf4;

    ISSUE_TILE(0, 0);
    ca0 = *(const float4*)(arow + klo);        // kt=0: klo+8 <= 32 < 500
    ca1 = *(const float4*)(arow + klo + 4);
    __syncthreads();   // barrier drains vmcnt -> tile 0 visible

    f32x4 acc[8] = {};

    for (int kt = 0; kt < 16; ++kt) {
        const int cb = kt & 1, nb = (kt + 1) & 1;

        float4 na0 = zf4, na1 = zf4;
        if (kt + 1 < 16) {
            ISSUE_TILE(kt + 1, nb);
            const int k = ((kt + 1) << 5) + klo;
            if (k + 8 <= F_IN) {
                na0 = *(const float4*)(arow + k);
                na1 = *(const float4*)(arow + k + 4);
            } else {
                float tmp[8];
#pragma unroll
                for (int i = 0; i < 8; ++i) tmp[i] = (k + i < F_IN) ? arow[k + i] : 0.f;
                na0 = make_float4(tmp[0], tmp[1], tmp[2], tmp[3]);
                na1 = make_float4(tmp[4], tmp[5], tmp[6], tmp[7]);
            }
        }

        const float av[8] = {ca0.x, ca0.y, ca0.z, ca0.w, ca1.x, ca1.y, ca1.z, ca1.w};
        s16x8 ahi, alo;
#pragma unroll
        for (int i = 0; i < 8; ++i) {
            unsigned h = bf16_rtne(av[i]);
            float fh = __uint_as_float(h << 16);
            unsigned l = bf16_rtne(av[i] - fh);
            ahi[i] = (short)h;
            alo[i] = (short)l;
        }

#pragma unroll
        for (int f = 0; f < 8; ++f) {
            const s16x8 bh = *(const s16x8*)&Bs[cb][(f << 10) + (lane << 3)];
            const s16x8 bl = *(const s16x8*)&Bs[cb][(f << 10) + 512 + (lane << 3)];
            acc[f] = __builtin_amdgcn_mfma_f32_16x16x32_bf16(ahi, bh, acc[f], 0, 0, 0);
            acc[f] = __builtin_amdgcn_mfma_f32_16x16x32_bf16(alo, bh, acc[f], 0, 0, 0);
            acc[f] = __builtin_amdgcn_mfma_f32_16x16x32_bf16(ahi, bl, acc[f], 0, 0, 0);
        }

        ca0 = na0;
        ca1 = na1;
        __syncthreads();
    }
#undef ISSUE_TILE

    // ---- epilogue: scale by isd[row], pack adjacent features via shfl ----
    const int orow = m0 + (kgrp << 2);
    float sr[4];
#pragma unroll
    for (int r = 0; r < 4; ++r) {
        const int m = orow + r;
        sr[r] = (m < M) ? isd[m] : 0.f;
    }
#pragma unroll
    for (int f = 0; f < 8; ++f) {
#pragma unroll
        for (int r = 0; r < 4; ++r) {
            float v = acc[f][r] * sr[r];
            float o = __shfl_xor(v, 1, 64);
            if (!(jcol & 1)) {
                const int m = orow + r;
                if (m < M)
                    hb[(size_t)m * 64 + (f << 3) + (jcol >> 1)] = bf16_pack2(v, o);
            }
        }
    }
}

// ---------------- fused gather + zlin, TWO waves per node (round-5 proven, 82 us) ----------------

__device__ __forceinline__ void gather_range(const unsigned* __restrict__ hh,
                                             const int* __restrict__ csr_src,
                                             int lane, int e, int end,
                                             float& accx, float& accy) {
    int s[8], t[8];
    bool have = (e + 8 <= end);
    if (have) {
#pragma unroll
        for (int i = 0; i < 8; ++i) s[i] = csr_src[e + i];
    }
    while (have) {
        unsigned v[8];
#pragma unroll
        for (int i = 0; i < 8; ++i) v[i] = hh[(size_t)s[i] * 64 + lane];
        const int ne = e + 8;
        const bool nhave = (ne + 8 <= end);
        if (nhave) {
#pragma unroll
            for (int i = 0; i < 8; ++i) t[i] = csr_src[ne + i];
        }
#pragma unroll
        for (int i = 0; i < 8; ++i) {
            accx += bf_lo(v[i]);
            accy += bf_hi(v[i]);
        }
#pragma unroll
        for (int i = 0; i < 8; ++i) s[i] = t[i];
        e = ne;
        have = nhave;
    }
    // masked tail batch (<8): all loads independent, compile-time indexing only
    if (e < end) {
        const int last = end - 1;
        int ss[8];
        unsigned vv[8];
#pragma unroll
        for (int i = 0; i < 8; ++i) ss[i] = csr_src[(e + i < end) ? e + i : last];
#pragma unroll
        for (int i = 0; i < 8; ++i) vv[i] = hh[(size_t)ss[i] * 64 + lane];
#pragma unroll
        for (int i = 0; i < 8; ++i) {
            if (e + i < end) {
                accx += bf_lo(vv[i]);
                accy += bf_hi(vv[i]);
            }
        }
    }
}

__global__ __launch_bounds__(256) void k_gather_fused2(const unsigned* __restrict__ hh,
                                                       const int* __restrict__ rowptr,
                                                       const int* __restrict__ csr_src,
                                                       const float* __restrict__ isd,
                                                       const float* __restrict__ Wc,
                                                       float* __restrict__ z) {
    __shared__ float2 part[2][64];
    const int tid = threadIdx.x;
    const int lane = tid & 63;
    const int waveid = tid >> 6;         // 0..3
    const int slot = waveid >> 1;        // node slot 0..1
    const int half = waveid & 1;         // 0 = primary, 1 = secondary
    const int node = (blockIdx.x << 1) + slot;   // < 50000 always (grid=25000)

    const int e0 = rowptr[node], e1 = rowptr[node + 1];
    const int mid = e0 + ((e1 - e0) >> 1);

    float accx = 0.f, accy = 0.f;
    if (half == 0) {
        const unsigned a = hh[(size_t)node * 64 + lane];   // self-loop: g_i
        accx = bf_lo(a);
        accy = bf_hi(a);
        gather_range(hh, csr_src, lane, e0, mid, accx, accy);
    } else {
        gather_range(hh, csr_src, lane, mid, e1, accx, accy);
        part[slot][lane] = make_float2(accx, accy);
    }
    __syncthreads();
    if (half == 1) return;

    const float2 pb = part[slot][lane];
    accx += pb.x;
    accy += pb.y;

    // layer-1 output = relu(si * acc); project; store zg = si * (proj) for layer 2
    const float si = isd[node];
    const float rx = fmaxf(accx * si, 0.f), ry = fmaxf(accy * si, 0.f);
    float p[16];
#pragma unroll
    for (int c = 0; c < 16; ++c) {
        const float2 wc = *(const float2*)(Wc + c * 128 + (lane << 1));
        p[c] = rx * wc.x + ry * wc.y;
    }
#pragma unroll
    for (int m = 1; m < 64; m <<= 1) {
#pragma unroll
        for (int c = 0; c < 16; ++c) p[c] += __shfl_xor(p[c], m, 64);
    }
    if (lane == 0) {
        float* zr = z + (size_t)node * 16;
        *(float4*)(zr + 0)  = make_float4(si * p[0],  si * p[1],  si * p[2],  si * p[3]);
        *(float4*)(zr + 4)  = make_float4(si * p[4],  si * p[5],  si * p[6],  si * p[7]);
        *(float4*)(zr + 8)  = make_float4(si * p[8],  si * p[9],  si * p[10], si * p[11]);
        *(float4*)(zr + 12) = make_float4(si * p[12], si * p[13], si * p[14], si * p[15]);
    }
}

// ---------------- gather16: ONE WAVE PER NODE (round-8, ~neutral vs old; kept) ----

__global__ __launch_bounds__(256) void k_gather16w(const float* __restrict__ zg,
                                                   const int* __restrict__ rowptr,
                                                   const int* __restrict__ csr_src,
                                                   const float* __restrict__ isd,
                                                   float* __restrict__ out) {
    const int tid = threadIdx.x;
    const int lane = tid & 63;
    const int node = (blockIdx.x << 2) + (tid >> 6);   // grid = 12500, exact
    const int f = lane & 15;
    const int slot = lane >> 4;

    const int e0 = rowptr[node];
    const int end = rowptr[node + 1];

    float acc = 0.f;
    if (e0 < end) {
        const int last = end - 1;
        for (int base = e0; base < end; base += 32) {
            int ss[8];
#pragma unroll
            for (int i = 0; i < 8; ++i) {
                const int idx = base + (i << 2) + slot;
                ss[i] = csr_src[(idx <= last) ? idx : last];   // clamp: dups are cache hits
            }
            float vv[8];
#pragma unroll
            for (int i = 0; i < 8; ++i) vv[i] = zg[(size_t)ss[i] * 16 + f];
#pragma unroll
            for (int i = 0; i < 8; ++i)
                if (base + (i << 2) + slot <= last) acc += vv[i];
        }
    }
    // reduce across the 4 edge slots (lanes l, l^16, l^32, l^48 share feature f)
    acc += __shfl_xor(acc, 16, 64);
    acc += __shfl_xor(acc, 32, 64);
    // self-loop + final scale
    const float si = isd[node];
    acc = (acc + zg[(size_t)node * 16 + f]) * si;
    if (lane < 16) out[(size_t)node * 16 + f] = acc;
}

// ---------------- fallback (round-1 atomic path, all fp32) ----------------

__global__ void k_deg_init(float* __restrict__ deg) {
    int i = blockIdx.x * 256 + threadIdx.x;
    if (i < N_NODES) deg[i] = 1.0f;
}
__global__ void k_deg_count(const int* __restrict__ dst, float* __restrict__ deg, int E) {
    int e = blockIdx.x * 256 + threadIdx.x;
    if (e < E) atomicAdd(&deg[dst[e]], 1.0f);
}
__global__ void k_rsqrt(float* __restrict__ deg) {
    int i = blockIdx.x * 256 + threadIdx.x;
    if (i < N_NODES) deg[i] = rsqrtf(deg[i]);
}
__global__ void k_agg_init(const float4* __restrict__ h, const float* __restrict__ isd,
                           float4* __restrict__ agg) {
    int t = blockIdx.x * 256 + threadIdx.x;
    if (t < N_NODES * (F_HID / 4)) {
        int row = t >> 5;
        float s = isd[row];
        s = s * s;
        float4 v = h[t];
        v.x *= s; v.y *= s; v.z *= s; v.w *= s;
        agg[t] = v;
    }
}
__global__ void k_scatter(const float4* __restrict__ h, const int* __restrict__ src,
                          const int* __restrict__ dst, const float* __restrict__ isd,
                          float* __restrict__ agg, int E) {
    int t = blockIdx.x * 256 + threadIdx.x;
    int e = t >> 5, q = t & 31;
    if (e >= E) return;
    int s = src[e], d = dst[e];
    float norm = isd[s] * isd[d];
    float4 v = h[(long long)s * 32 + q];
    float* out = agg + (long long)d * F_HID + q * 4;
    atomicAdd(out + 0, v.x * norm);
    atomicAdd(out + 1, v.y * norm);
    atomicAdd(out + 2, v.z * norm);
    atomicAdd(out + 3, v.w * norm);
}
template <int BM, int BN, int BK, int TM, int TN, bool RELU_A>
__global__ __launch_bounds__(256) void gemm_nt(const float* __restrict__ A,
                                               const float* __restrict__ B,
                                               float* __restrict__ C,
                                               int M, int N, int K) {
    __shared__ float As[BK][BM + 1];
    __shared__ float Bs[BK][BN + 1];
    const int tid = threadIdx.x;
    const int NTX = BN / TN;
    const int tx = tid % NTX;
    const int ty = tid / NTX;
    const int m0 = blockIdx.x * BM;
    const int n0 = blockIdx.y * BN;
    float acc[TM][TN] = {};
    for (int k0 = 0; k0 < K; k0 += BK) {
        for (int idx = tid; idx < BM * BK; idx += 256) {
            int m = idx / BK, k = idx % BK;
            int gm = m0 + m;
            float v = (gm < M) ? A[(long long)gm * K + k0 + k] : 0.0f;
            if (RELU_A) v = fmaxf(v, 0.0f);
            As[k][m] = v;
        }
        for (int idx = tid; idx < BN * BK; idx += 256) {
            int n = idx / BK, k = idx % BK;
            int gn = n0 + n;
            Bs[k][n] = (gn < N) ? B[(long long)gn * K + k0 + k] : 0.0f;
        }
        __syncthreads();
        for (int k = 0; k < BK; ++k) {
            float a[TM], b[TN];
#pragma unroll
            for (int r = 0; r < TM; ++r) a[r] = As[k][ty * TM + r];
#pragma unroll
            for (int c = 0; c < TN; ++c) b[c] = Bs[k][c * NTX + tx];
#pragma unroll
            for (int r = 0; r < TM; ++r)
#pragma unroll
                for (int c = 0; c < TN; ++c) acc[r][c] += a[r] * b[c];
        }
        __syncthreads();
    }
#pragma unroll
    for (int r = 0; r < TM; ++r) {
        int gm = m0 + ty * TM + r;
        if (gm >= M) continue;
#pragma unroll
        for (int c = 0; c < TN; ++c) {
            int gn = n0 + c * NTX + tx;
            if (gn < N) C[(long long)gm * N + gn] = acc[r][c];
        }
    }
}
__global__ __launch_bounds__(256) void gemm_lin(const float* __restrict__ A,
                                                const float* __restrict__ W,
                                                float* __restrict__ C, int M) {
    __shared__ float Ws[16][129];
    __shared__ float As[16][129];
    const int tid = threadIdx.x;
    for (int idx = tid; idx < 16 * 128; idx += 256) Ws[idx >> 7][idx & 127] = W[idx];
    const int m0 = blockIdx.x * 16;
    for (int idx = tid; idx < 16 * 128; idx += 256) {
        int r = idx >> 7, k = idx & 127;
        int gm = m0 + r;
        As[r][k] = (gm < M) ? A[(long long)gm * 128 + k] : 0.0f;
    }
    __syncthreads();
    const int tc = tid & 15, tr = tid >> 4;
    float s = 0.f;
#pragma unroll 8
    for (int k = 0; k < 128; ++k) s += As[tr][k] * Ws[tc][k];
    int gm = m0 + tr;
    if (gm < M) C[gm * 16 + tc] = s;
}

// ---------------- launcher ----------------

static inline size_t align256(size_t x) { return (x + 255) & ~(size_t)255; }

extern "C" void kernel_launch(void* const* d_in, const int* in_sizes, int n_in,
                              void* d_out, int out_size, void* d_ws, size_t ws_size,
                              hipStream_t stream) {
    const float* x    = (const float*)d_in[0];
    const int*   ei   = (const int*)d_in[1];
    const float* W1   = (const float*)d_in[2];
    const float* W2   = (const float*)d_in[3];
    const float* Wlin = (const float*)d_in[4];
    float* out = (float*)d_out;

    const int E = in_sizes[1] / 2;
    const int* src = ei;
    const int* dst = ei + E;

    // workspace layout
    char* ws = (char*)d_ws;
    size_t off = 0;
    float* isd  = (float*)(ws + off); off += align256((size_t)N_NODES * 4);
    float* Wc   = (float*)(ws + off); off += align256(16 * 128 * 4);
    float* bufA = (float*)(ws + off); off += align256((size_t)N_NODES * F_HID * 4);
    float* bufB = (float*)(ws + off); off += align256((size_t)N_NODES * F_HID * 4);
    int*   hist    = (int*)(ws + off); off += align256((size_t)N_NODES * 4);
    int*   rowptr  = (int*)(ws + off); off += align256(((size_t)N_NODES + 1) * 4);
    int*   blksum  = (int*)(ws + off); off += align256(256 * 4);
    int*   csr_src = (int*)(ws + off); off += align256((size_t)E * 4);
    int*   cursor  = (int*)(ws + off); off += align256((size_t)N_NODES * 4);
    ushort* wpk    = (ushort*)(ws + off); off += align256((size_t)16 * 8192 * 2);  // 256 KB
    const bool use_csr = (off <= ws_size);

    const int nblk_nodes = NSCAN_BLKS;
    const int nblk_edges = (E + 255) / 256;
    const int nblk_e4 = (E + 1023) / 1024;
    const int mtiles = (N_NODES + 63) / 64;

    if (use_csr) {
        unsigned* hb = (unsigned*)bufB;   // [N][64] packed bf16x2, pre-scaled by isd
        float*    z  = bufA;              // [N][16] fp32, pre-scaled by isd

        // 1. CSR build (count-only hist + cursor reorder, 4 edges/thread)
        hipMemsetAsync(hist, 0, (size_t)N_NODES * 4, stream);
        k_hist4<<<nblk_e4, 256, 0, stream>>>(dst, hist, E);
        k_scan_local<<<nblk_nodes, 256, 0, stream>>>(hist, rowptr, blksum);
        k_scan_blk<<<1, 256, 0, stream>>>(blksum);
        k_finalize<<<nblk_nodes, 256, 0, stream>>>(hist, rowptr, blksum, isd, cursor, E);
        k_reorder4<<<nblk_e4, 256, 0, stream>>>(src, dst, cursor, csr_src, E);
        // 2. Wc = Wlin @ W2 ; W1 fragment-major bf16 hi/lo pack (padded K=512)
        k_wc<<<16, 128, 0, stream>>>(W2, Wlin, Wc);
        k_w1pack<<<32, 256, 0, stream>>>(W1, wpk);
        // 3. g = isd * (x @ W1^T) -> bf16 via MFMA (glds-staged B, dbuf, A prefetch)
        gemm1_mfma5<<<mtiles, 256, 0, stream>>>(x, wpk, isd, hb, N_NODES);
        // 4+5. zg = isd * ( relu(isd * (sum g)) @ Wc^T )   (fused, 2 waves/node)
        k_gather_fused2<<<N_NODES / 2, 256, 0, stream>>>(
            hb, rowptr, csr_src, isd, Wc, z);
        // 6. out = isd * (sum zg)   (wave-per-node)
        k_gather16w<<<N_NODES / 4, 256, 0, stream>>>(
            z, rowptr, csr_src, isd, out);
    } else {
        // fallback: atomic scatter path (fp32)
        const int nblk_feat = (N_NODES * (F_HID / 4) + 255) / 256;
        const int nblk_scatter = (int)(((long long)E * 32 + 255) / 256);
        k_deg_init<<<(N_NODES + 255) / 256, 256, 0, stream>>>(isd);
        k_deg_count<<<nblk_edges, 256, 0, stream>>>(dst, isd, E);
        k_rsqrt<<<(N_NODES + 255) / 256, 256, 0, stream>>>(isd);
        gemm_nt<64, 128, 20, 4, 8, false>
            <<<dim3(mtiles, 1), 256, 0, stream>>>(x, W1, bufA, N_NODES, F_HID, F_IN);
        k_agg_init<<<nblk_feat, 256, 0, stream>>>((const float4*)bufA, isd, (float4*)bufB);
        k_scatter<<<nblk_scatter, 256, 0, stream>>>((const float4*)bufA, src, dst, isd, bufB, E);
        gemm_nt<64, 128, 16, 4, 8, true>
            <<<dim3(mtiles, 1), 256, 0, stream>>>(bufB, W2, bufA, N_NODES, F_HID, F_HID);
        k_agg_init<<<nblk_feat, 256, 0, stream>>>((const float4*)bufA, isd, (float4*)bufB);
        k_scatter<<<nblk_scatter, 256, 0, stream>>>((const float4*)bufA, src, dst, isd, bufB, E);
        gemm_lin<<<(N_NODES + 15) / 16, 256, 0, stream>>>(bufB, Wlin, out, N_NODES);
    }
}

// Round 10
// 408.828 us; speedup vs baseline: 1.2286x; 1.2286x over previous
//
#include <hip/hip_runtime.h>

#define N_NODES 50000
#define F_IN 500
#define F_HID 128
#define F_OUT 16
#define NSCAN_BLKS ((N_NODES + 255) / 256)   // 196

// ---------------- bf16 helpers (RTNE pack, shift decode) ----------------

__device__ __forceinline__ unsigned bf16_pack2(float a, float b) {
    unsigned ua = __float_as_uint(a);
    unsigned ub = __float_as_uint(b);
    ua = (ua + 0x7fffu + ((ua >> 16) & 1u)) >> 16;
    ub = (ub + 0x7fffu + ((ub >> 16) & 1u)) >> 16;
    return ua | (ub << 16);
}
__device__ __forceinline__ float bf_lo(unsigned v) { return __uint_as_float(v << 16); }
__device__ __forceinline__ float bf_hi(unsigned v) { return __uint_as_float(v & 0xffff0000u); }

__device__ __forceinline__ unsigned bf16_rtne(float a) {
    unsigned u = __float_as_uint(a);
    return (u + 0x7fffu + ((u >> 16) & 1u)) >> 16;
}

// ---------------- CSR build: rank-based two-pass (round-8 proven structure),
// now 4 edges/thread with int4 loads.
// Round-9 lesson: cursor-style reorder (scatter DEPENDS on atomic return) chains
// two L2 round trips per edge -> 148 us. Rank-based split keeps the atomic's
// dependent write COALESCED (rank[e]) and reorder's scatter depends only on two
// parallel loads. Vectorization adds 4x memory-level parallelism to both passes.

__global__ __launch_bounds__(256) void k_hist_rank4(const int* __restrict__ dst,
                                                    int* __restrict__ hist,
                                                    int* __restrict__ rank, int E) {
    const int base = (blockIdx.x * 256 + threadIdx.x) << 2;
    if (base + 4 <= E) {
        const int4 d = *(const int4*)(dst + base);
        int4 r;
        r.x = atomicAdd(&hist[d.x], 1);
        r.y = atomicAdd(&hist[d.y], 1);
        r.z = atomicAdd(&hist[d.z], 1);
        r.w = atomicAdd(&hist[d.w], 1);
        *(int4*)(rank + base) = r;      // coalesced dependent write
    } else {
        for (int i = base; i < E; ++i) rank[i] = atomicAdd(&hist[dst[i]], 1);
    }
}

__global__ __launch_bounds__(256) void k_scan_local(const int* __restrict__ hist,
                                                    int* __restrict__ rowptr,
                                                    int* __restrict__ blksum) {
    __shared__ int s[256];
    const int tid = threadIdx.x;
    const int i = blockIdx.x * 256 + tid;
    int v = (i < N_NODES) ? hist[i] : 0;
    s[tid] = v;
    __syncthreads();
#pragma unroll
    for (int ofs = 1; ofs < 256; ofs <<= 1) {
        int t = (tid >= ofs) ? s[tid - ofs] : 0;
        __syncthreads();
        if (tid >= ofs) s[tid] += t;
        __syncthreads();
    }
    if (i < N_NODES) rowptr[i] = s[tid] - v;
    if (tid == 255) blksum[blockIdx.x] = s[255];
}

__global__ __launch_bounds__(256) void k_scan_blk(int* __restrict__ blksum) {
    __shared__ int s[256];
    const int tid = threadIdx.x;
    int v = (tid < NSCAN_BLKS) ? blksum[tid] : 0;
    s[tid] = v;
    __syncthreads();
#pragma unroll
    for (int ofs = 1; ofs < 256; ofs <<= 1) {
        int t = (tid >= ofs) ? s[tid - ofs] : 0;
        __syncthreads();
        if (tid >= ofs) s[tid] += t;
        __syncthreads();
    }
    if (tid < NSCAN_BLKS) blksum[tid] = s[tid] - v;
}

__global__ void k_finalize(const int* __restrict__ hist, int* __restrict__ rowptr,
                           const int* __restrict__ blksum, float* __restrict__ isd, int E) {
    int i = blockIdx.x * 256 + threadIdx.x;
    if (i < N_NODES) {
        rowptr[i] = rowptr[i] + blksum[i >> 8];
        isd[i] = rsqrtf((float)(hist[i] + 1));  // +1 self-loop
    }
    if (i == 0) rowptr[N_NODES] = E;
}

__global__ __launch_bounds__(256) void k_reorder4r(const int* __restrict__ src,
                                                   const int* __restrict__ dst,
                                                   const int* __restrict__ rank,
                                                   const int* __restrict__ rowptr,
                                                   int* __restrict__ csr_src, int E) {
    const int base = (blockIdx.x * 256 + threadIdx.x) << 2;
    if (base + 4 <= E) {
        const int4 d = *(const int4*)(dst + base);
        const int4 s = *(const int4*)(src + base);
        const int4 r = *(const int4*)(rank + base);
        const int p0 = rowptr[d.x] + r.x;   // 4 parallel L2-resident gathers
        const int p1 = rowptr[d.y] + r.y;
        const int p2 = rowptr[d.z] + r.z;
        const int p3 = rowptr[d.w] + r.w;
        csr_src[p0] = s.x;                  // 4 independent scatters
        csr_src[p1] = s.y;
        csr_src[p2] = s.z;
        csr_src[p3] = s.w;
    } else {
        for (int i = base; i < E; ++i) csr_src[rowptr[dst[i]] + rank[i]] = src[i];
    }
}

// ---------------- Wc = Wlin @ W2  [16,128] ----------------

__global__ void k_wc(const float* __restrict__ W2, const float* __restrict__ Wlin,
                     float* __restrict__ Wc) {
    const int c = blockIdx.x;       // 0..15
    const int j = threadIdx.x;      // 0..127
    const float* wl = Wlin + c * 128;
    float acc = 0.f;
#pragma unroll 4
    for (int k = 0; k < 128; ++k) acc += wl[k] * W2[k * 128 + j];
    Wc[c * 128 + j] = acc;
}

// ---------------- W1 pack: fragment-major bf16 hi/lo, padded K 500->512 ----------------

__global__ __launch_bounds__(256) void k_w1pack(const float* __restrict__ W1,
                                                ushort* __restrict__ wpk) {
    int t = blockIdx.x * 256 + threadIdx.x;   // (kt*8+f)*64 + lane ; 8192 total
    if (t >= 8192) return;
    const int lane = t & 63;
    const int fkt = t >> 6;
    const int f = fkt & 7;
    const int kt = fkt >> 3;
    const int n = (f << 4) + (lane & 15);
    const int kb = (kt << 5) + ((lane >> 4) << 3);
    ushort h8[8], l8[8];
#pragma unroll
    for (int j = 0; j < 8; ++j) {
        const int k = kb + j;
        float v = (k < F_IN) ? W1[n * F_IN + k] : 0.f;
        unsigned h = bf16_rtne(v);
        float fh = __uint_as_float(h << 16);
        unsigned l = bf16_rtne(v - fh);      // Dekker residual, exact in fp32
        h8[j] = (ushort)h;
        l8[j] = (ushort)l;
    }
    const size_t base = ((size_t)fkt << 10);         // (kt*8+f)*1024 elements
    *(uint4*)(wpk + base + (lane << 3))       = *(const uint4*)h8;
    *(uint4*)(wpk + base + 512 + (lane << 3)) = *(const uint4*)l8;
}

// ---------------- GEMM1 via MFMA + glds-staged B: g[M,128](bf16) = isd * (A @ W1^T) ----
// (round-4/5 proven) 3-pass Dekker split; glds w=16; dbuf; one barrier/kt.

typedef __attribute__((ext_vector_type(8))) short s16x8;
typedef __attribute__((ext_vector_type(4))) float f32x4;

typedef const __attribute__((address_space(1))) unsigned u32_glb;
typedef __attribute__((address_space(3))) unsigned u32_lds;

__device__ __forceinline__ void glds16(const void* g, void* l) {
    __builtin_amdgcn_global_load_lds((u32_glb*)g, (u32_lds*)l, 16, 0, 0);
}

__global__ __launch_bounds__(256) void gemm1_mfma5(const float* __restrict__ A,
                                                   const ushort* __restrict__ wpk,
                                                   const float* __restrict__ isd,
                                                   unsigned* __restrict__ hb, int M) {
    __shared__ __align__(16) ushort Bs[2][8192];   // 2 x 16 KB

    const int tid = threadIdx.x;
    const int lane = tid & 63;
    const int wave = tid >> 6;                // 0..3
    const int jcol = lane & 15;
    const int kgrp = lane >> 4;
    const int klo  = kgrp << 3;

    const int m0  = blockIdx.x * 64 + wave * 16;
    const int arw = m0 + jcol;
    const float* arow = A + (size_t)((arw < M) ? arw : (M - 1)) * F_IN;

#define ISSUE_TILE(KT, B)                                                        \
    {                                                                            \
        const ushort* tb_ = wpk + ((size_t)(KT) << 13);                          \
        _Pragma("unroll") for (int c_ = 0; c_ < 4; ++c_) {                       \
            glds16(tb_ + ((c_ * 256 + wave * 64 + lane) << 3),                   \
                   &Bs[B][(c_ * 256 + wave * 64) << 3]);                         \
        }                                                                        \
    }

    const float4 zf4 = make_float4(0.f, 0.f, 0.f, 0.f);
    float4 ca0 = zf4, ca1 = zf4;

    ISSUE_TILE(0, 0);
    ca0 = *(const float4*)(arow + klo);        // kt=0: klo+8 <= 32 < 500
    ca1 = *(const float4*)(arow + klo + 4);
    __syncthreads();   // barrier drains vmcnt -> tile 0 visible

    f32x4 acc[8] = {};

    for (int kt = 0; kt < 16; ++kt) {
        const int cb = kt & 1, nb = (kt + 1) & 1;

        float4 na0 = zf4, na1 = zf4;
        if (kt + 1 < 16) {
            ISSUE_TILE(kt + 1, nb);
            const int k = ((kt + 1) << 5) + klo;
            if (k + 8 <= F_IN) {
                na0 = *(const float4*)(arow + k);
                na1 = *(const float4*)(arow + k + 4);
            } else {
                float tmp[8];
#pragma unroll
                for (int i = 0; i < 8; ++i) tmp[i] = (k + i < F_IN) ? arow[k + i] : 0.f;
                na0 = make_float4(tmp[0], tmp[1], tmp[2], tmp[3]);
                na1 = make_float4(tmp[4], tmp[5], tmp[6], tmp[7]);
            }
        }

        const float av[8] = {ca0.x, ca0.y, ca0.z, ca0.w, ca1.x, ca1.y, ca1.z, ca1.w};
        s16x8 ahi, alo;
#pragma unroll
        for (int i = 0; i < 8; ++i) {
            unsigned h = bf16_rtne(av[i]);
            float fh = __uint_as_float(h << 16);
            unsigned l = bf16_rtne(av[i] - fh);
            ahi[i] = (short)h;
            alo[i] = (short)l;
        }

#pragma unroll
        for (int f = 0; f < 8; ++f) {
            const s16x8 bh = *(const s16x8*)&Bs[cb][(f << 10) + (lane << 3)];
            const s16x8 bl = *(const s16x8*)&Bs[cb][(f << 10) + 512 + (lane << 3)];
            acc[f] = __builtin_amdgcn_mfma_f32_16x16x32_bf16(ahi, bh, acc[f], 0, 0, 0);
            acc[f] = __builtin_amdgcn_mfma_f32_16x16x32_bf16(alo, bh, acc[f], 0, 0, 0);
            acc[f] = __builtin_amdgcn_mfma_f32_16x16x32_bf16(ahi, bl, acc[f], 0, 0, 0);
        }

        ca0 = na0;
        ca1 = na1;
        __syncthreads();
    }
#undef ISSUE_TILE

    // ---- epilogue: scale by isd[row], pack adjacent features via shfl ----
    const int orow = m0 + (kgrp << 2);
    float sr[4];
#pragma unroll
    for (int r = 0; r < 4; ++r) {
        const int m = orow + r;
        sr[r] = (m < M) ? isd[m] : 0.f;
    }
#pragma unroll
    for (int f = 0; f < 8; ++f) {
#pragma unroll
        for (int r = 0; r < 4; ++r) {
            float v = acc[f][r] * sr[r];
            float o = __shfl_xor(v, 1, 64);
            if (!(jcol & 1)) {
                const int m = orow + r;
                if (m < M)
                    hb[(size_t)m * 64 + (f << 3) + (jcol >> 1)] = bf16_pack2(v, o);
            }
        }
    }
}

// ---------------- fused gather + zlin, TWO waves per node (round-5 proven, 82 us) ----------------

__device__ __forceinline__ void gather_range(const unsigned* __restrict__ hh,
                                             const int* __restrict__ csr_src,
                                             int lane, int e, int end,
                                             float& accx, float& accy) {
    int s[8], t[8];
    bool have = (e + 8 <= end);
    if (have) {
#pragma unroll
        for (int i = 0; i < 8; ++i) s[i] = csr_src[e + i];
    }
    while (have) {
        unsigned v[8];
#pragma unroll
        for (int i = 0; i < 8; ++i) v[i] = hh[(size_t)s[i] * 64 + lane];
        const int ne = e + 8;
        const bool nhave = (ne + 8 <= end);
        if (nhave) {
#pragma unroll
            for (int i = 0; i < 8; ++i) t[i] = csr_src[ne + i];
        }
#pragma unroll
        for (int i = 0; i < 8; ++i) {
            accx += bf_lo(v[i]);
            accy += bf_hi(v[i]);
        }
#pragma unroll
        for (int i = 0; i < 8; ++i) s[i] = t[i];
        e = ne;
        have = nhave;
    }
    // masked tail batch (<8): all loads independent, compile-time indexing only
    if (e < end) {
        const int last = end - 1;
        int ss[8];
        unsigned vv[8];
#pragma unroll
        for (int i = 0; i < 8; ++i) ss[i] = csr_src[(e + i < end) ? e + i : last];
#pragma unroll
        for (int i = 0; i < 8; ++i) vv[i] = hh[(size_t)ss[i] * 64 + lane];
#pragma unroll
        for (int i = 0; i < 8; ++i) {
            if (e + i < end) {
                accx += bf_lo(vv[i]);
                accy += bf_hi(vv[i]);
            }
        }
    }
}

__global__ __launch_bounds__(256) void k_gather_fused2(const unsigned* __restrict__ hh,
                                                       const int* __restrict__ rowptr,
                                                       const int* __restrict__ csr_src,
                                                       const float* __restrict__ isd,
                                                       const float* __restrict__ Wc,
                                                       float* __restrict__ z) {
    __shared__ float2 part[2][64];
    const int tid = threadIdx.x;
    const int lane = tid & 63;
    const int waveid = tid >> 6;         // 0..3
    const int slot = waveid >> 1;        // node slot 0..1
    const int half = waveid & 1;         // 0 = primary, 1 = secondary
    const int node = (blockIdx.x << 1) + slot;   // < 50000 always (grid=25000)

    const int e0 = rowptr[node], e1 = rowptr[node + 1];
    const int mid = e0 + ((e1 - e0) >> 1);

    float accx = 0.f, accy = 0.f;
    if (half == 0) {
        const unsigned a = hh[(size_t)node * 64 + lane];   // self-loop: g_i
        accx = bf_lo(a);
        accy = bf_hi(a);
        gather_range(hh, csr_src, lane, e0, mid, accx, accy);
    } else {
        gather_range(hh, csr_src, lane, mid, e1, accx, accy);
        part[slot][lane] = make_float2(accx, accy);
    }
    __syncthreads();
    if (half == 1) return;

    const float2 pb = part[slot][lane];
    accx += pb.x;
    accy += pb.y;

    // layer-1 output = relu(si * acc); project; store zg = si * (proj) for layer 2
    const float si = isd[node];
    const float rx = fmaxf(accx * si, 0.f), ry = fmaxf(accy * si, 0.f);
    float p[16];
#pragma unroll
    for (int c = 0; c < 16; ++c) {
        const float2 wc = *(const float2*)(Wc + c * 128 + (lane << 1));
        p[c] = rx * wc.x + ry * wc.y;
    }
#pragma unroll
    for (int m = 1; m < 64; m <<= 1) {
#pragma unroll
        for (int c = 0; c < 16; ++c) p[c] += __shfl_xor(p[c], m, 64);
    }
    if (lane == 0) {
        float* zr = z + (size_t)node * 16;
        *(float4*)(zr + 0)  = make_float4(si * p[0],  si * p[1],  si * p[2],  si * p[3]);
        *(float4*)(zr + 4)  = make_float4(si * p[4],  si * p[5],  si * p[6],  si * p[7]);
        *(float4*)(zr + 8)  = make_float4(si * p[8],  si * p[9],  si * p[10], si * p[11]);
        *(float4*)(zr + 12) = make_float4(si * p[12], si * p[13], si * p[14], si * p[15]);
    }
}

// ---------------- gather16: ONE WAVE PER NODE (round-8, kept) ----------------

__global__ __launch_bounds__(256) void k_gather16w(const float* __restrict__ zg,
                                                   const int* __restrict__ rowptr,
                                                   const int* __restrict__ csr_src,
                                                   const float* __restrict__ isd,
                                                   float* __restrict__ out) {
    const int tid = threadIdx.x;
    const int lane = tid & 63;
    const int node = (blockIdx.x << 2) + (tid >> 6);   // grid = 12500, exact
    const int f = lane & 15;
    const int slot = lane >> 4;

    const int e0 = rowptr[node];
    const int end = rowptr[node + 1];

    float acc = 0.f;
    if (e0 < end) {
        const int last = end - 1;
        for (int base = e0; base < end; base += 32) {
            int ss[8];
#pragma unroll
            for (int i = 0; i < 8; ++i) {
                const int idx = base + (i << 2) + slot;
                ss[i] = csr_src[(idx <= last) ? idx : last];   // clamp: dups are cache hits
            }
            float vv[8];
#pragma unroll
            for (int i = 0; i < 8; ++i) vv[i] = zg[(size_t)ss[i] * 16 + f];
#pragma unroll
            for (int i = 0; i < 8; ++i)
                if (base + (i << 2) + slot <= last) acc += vv[i];
        }
    }
    // reduce across the 4 edge slots (lanes l, l^16, l^32, l^48 share feature f)
    acc += __shfl_xor(acc, 16, 64);
    acc += __shfl_xor(acc, 32, 64);
    // self-loop + final scale
    const float si = isd[node];
    acc = (acc + zg[(size_t)node * 16 + f]) * si;
    if (lane < 16) out[(size_t)node * 16 + f] = acc;
}

// ---------------- fallback (round-1 atomic path, all fp32) ----------------

__global__ void k_deg_init(float* __restrict__ deg) {
    int i = blockIdx.x * 256 + threadIdx.x;
    if (i < N_NODES) deg[i] = 1.0f;
}
__global__ void k_deg_count(const int* __restrict__ dst, float* __restrict__ deg, int E) {
    int e = blockIdx.x * 256 + threadIdx.x;
    if (e < E) atomicAdd(&deg[dst[e]], 1.0f);
}
__global__ void k_rsqrt(float* __restrict__ deg) {
    int i = blockIdx.x * 256 + threadIdx.x;
    if (i < N_NODES) deg[i] = rsqrtf(deg[i]);
}
__global__ void k_agg_init(const float4* __restrict__ h, const float* __restrict__ isd,
                           float4* __restrict__ agg) {
    int t = blockIdx.x * 256 + threadIdx.x;
    if (t < N_NODES * (F_HID / 4)) {
        int row = t >> 5;
        float s = isd[row];
        s = s * s;
        float4 v = h[t];
        v.x *= s; v.y *= s; v.z *= s; v.w *= s;
        agg[t] = v;
    }
}
__global__ void k_scatter(const float4* __restrict__ h, const int* __restrict__ src,
                          const int* __restrict__ dst, const float* __restrict__ isd,
                          float* __restrict__ agg, int E) {
    int t = blockIdx.x * 256 + threadIdx.x;
    int e = t >> 5, q = t & 31;
    if (e >= E) return;
    int s = src[e], d = dst[e];
    float norm = isd[s] * isd[d];
    float4 v = h[(long long)s * 32 + q];
    float* out = agg + (long long)d * F_HID + q * 4;
    atomicAdd(out + 0, v.x * norm);
    atomicAdd(out + 1, v.y * norm);
    atomicAdd(out + 2, v.z * norm);
    atomicAdd(out + 3, v.w * norm);
}
template <int BM, int BN, int BK, int TM, int TN, bool RELU_A>
__global__ __launch_bounds__(256) void gemm_nt(const float* __restrict__ A,
                                               const float* __restrict__ B,
                                               float* __restrict__ C,
                                               int M, int N, int K) {
    __shared__ float As[BK][BM + 1];
    __shared__ float Bs[BK][BN + 1];
    const int tid = threadIdx.x;
    const int NTX = BN / TN;
    const int tx = tid % NTX;
    const int ty = tid / NTX;
    const int m0 = blockIdx.x * BM;
    const int n0 = blockIdx.y * BN;
    float acc[TM][TN] = {};
    for (int k0 = 0; k0 < K; k0 += BK) {
        for (int idx = tid; idx < BM * BK; idx += 256) {
            int m = idx / BK, k = idx % BK;
            int gm = m0 + m;
            float v = (gm < M) ? A[(long long)gm * K + k0 + k] : 0.0f;
            if (RELU_A) v = fmaxf(v, 0.0f);
            As[k][m] = v;
        }
        for (int idx = tid; idx < BN * BK; idx += 256) {
            int n = idx / BK, k = idx % BK;
            int gn = n0 + n;
            Bs[k][n] = (gn < N) ? B[(long long)gn * K + k0 + k] : 0.0f;
        }
        __syncthreads();
        for (int k = 0; k < BK; ++k) {
            float a[TM], b[TN];
#pragma unroll
            for (int r = 0; r < TM; ++r) a[r] = As[k][ty * TM + r];
#pragma unroll
            for (int c = 0; c < TN; ++c) b[c] = Bs[k][c * NTX + tx];
#pragma unroll
            for (int r = 0; r < TM; ++r)
#pragma unroll
                for (int c = 0; c < TN; ++c) acc[r][c] += a[r] * b[c];
        }
        __syncthreads();
    }
#pragma unroll
    for (int r = 0; r < TM; ++r) {
        int gm = m0 + ty * TM + r;
        if (gm >= M) continue;
#pragma unroll
        for (int c = 0; c < TN; ++c) {
            int gn = n0 + c * NTX + tx;
            if (gn < N) C[(long long)gm * N + gn] = acc[r][c];
        }
    }
}
__global__ __launch_bounds__(256) void gemm_lin(const float* __restrict__ A,
                                                const float* __restrict__ W,
                                                float* __restrict__ C, int M) {
    __shared__ float Ws[16][129];
    __shared__ float As[16][129];
    const int tid = threadIdx.x;
    for (int idx = tid; idx < 16 * 128; idx += 256) Ws[idx >> 7][idx & 127] = W[idx];
    const int m0 = blockIdx.x * 16;
    for (int idx = tid; idx < 16 * 128; idx += 256) {
        int r = idx >> 7, k = idx & 127;
        int gm = m0 + r;
        As[r][k] = (gm < M) ? A[(long long)gm * 128 + k] : 0.0f;
    }
    __syncthreads();
    const int tc = tid & 15, tr = tid >> 4;
    float s = 0.f;
#pragma unroll 8
    for (int k = 0; k < 128; ++k) s += As[tr][k] * Ws[tc][k];
    int gm = m0 + tr;
    if (gm < M) C[gm * 16 + tc] = s;
}

// ---------------- launcher ----------------

static inline size_t align256(size_t x) { return (x + 255) & ~(size_t)255; }

extern "C" void kernel_launch(void* const* d_in, const int* in_sizes, int n_in,
                              void* d_out, int out_size, void* d_ws, size_t ws_size,
                              hipStream_t stream) {
    const float* x    = (const float*)d_in[0];
    const int*   ei   = (const int*)d_in[1];
    const float* W1   = (const float*)d_in[2];
    const float* W2   = (const float*)d_in[3];
    const float* Wlin = (const float*)d_in[4];
    float* out = (float*)d_out;

    const int E = in_sizes[1] / 2;
    const int* src = ei;
    const int* dst = ei + E;

    // workspace layout
    char* ws = (char*)d_ws;
    size_t off = 0;
    float* isd  = (float*)(ws + off); off += align256((size_t)N_NODES * 4);
    float* Wc   = (float*)(ws + off); off += align256(16 * 128 * 4);
    float* bufA = (float*)(ws + off); off += align256((size_t)N_NODES * F_HID * 4);
    float* bufB = (float*)(ws + off); off += align256((size_t)N_NODES * F_HID * 4);
    int*   hist    = (int*)(ws + off); off += align256((size_t)N_NODES * 4);
    int*   rowptr  = (int*)(ws + off); off += align256(((size_t)N_NODES + 1) * 4);
    int*   blksum  = (int*)(ws + off); off += align256(256 * 4);
    int*   csr_src = (int*)(ws + off); off += align256((size_t)E * 4);
    int*   rank    = (int*)(ws + off); off += align256((size_t)E * 4);
    ushort* wpk    = (ushort*)(ws + off); off += align256((size_t)16 * 8192 * 2);  // 256 KB
    const bool use_csr = (off <= ws_size);

    const int nblk_nodes = NSCAN_BLKS;
    const int nblk_edges = (E + 255) / 256;
    const int nblk_e4 = (E + 1023) / 1024;
    const int mtiles = (N_NODES + 63) / 64;

    if (use_csr) {
        unsigned* hb = (unsigned*)bufB;   // [N][64] packed bf16x2, pre-scaled by isd
        float*    z  = bufA;              // [N][16] fp32, pre-scaled by isd

        // 1. CSR build (rank-based two-pass, 4 edges/thread)
        hipMemsetAsync(hist, 0, (size_t)N_NODES * 4, stream);
        k_hist_rank4<<<nblk_e4, 256, 0, stream>>>(dst, hist, rank, E);
        k_scan_local<<<nblk_nodes, 256, 0, stream>>>(hist, rowptr, blksum);
        k_scan_blk<<<1, 256, 0, stream>>>(blksum);
        k_finalize<<<nblk_nodes, 256, 0, stream>>>(hist, rowptr, blksum, isd, E);
        k_reorder4r<<<nblk_e4, 256, 0, stream>>>(src, dst, rank, rowptr, csr_src, E);
        // 2. Wc = Wlin @ W2 ; W1 fragment-major bf16 hi/lo pack (padded K=512)
        k_wc<<<16, 128, 0, stream>>>(W2, Wlin, Wc);
        k_w1pack<<<32, 256, 0, stream>>>(W1, wpk);
        // 3. g = isd * (x @ W1^T) -> bf16 via MFMA (glds-staged B, dbuf, A prefetch)
        gemm1_mfma5<<<mtiles, 256, 0, stream>>>(x, wpk, isd, hb, N_NODES);
        // 4+5. zg = isd * ( relu(isd * (sum g)) @ Wc^T )   (fused, 2 waves/node)
        k_gather_fused2<<<N_NODES / 2, 256, 0, stream>>>(
            hb, rowptr, csr_src, isd, Wc, z);
        // 6. out = isd * (sum zg)   (wave-per-node)
        k_gather16w<<<N_NODES / 4, 256, 0, stream>>>(
            z, rowptr, csr_src, isd, out);
    } else {
        // fallback: atomic scatter path (fp32)
        const int nblk_feat = (N_NODES * (F_HID / 4) + 255) / 256;
        const int nblk_scatter = (int)(((long long)E * 32 + 255) / 256);
        k_deg_init<<<(N_NODES + 255) / 256, 256, 0, stream>>>(isd);
        k_deg_count<<<nblk_edges, 256, 0, stream>>>(dst, isd, E);
        k_rsqrt<<<(N_NODES + 255) / 256, 256, 0, stream>>>(isd);
        gemm_nt<64, 128, 20, 4, 8, false>
            <<<dim3(mtiles, 1), 256, 0, stream>>>(x, W1, bufA, N_NODES, F_HID, F_IN);
        k_agg_init<<<nblk_feat, 256, 0, stream>>>((const float4*)bufA, isd, (float4*)bufB);
        k_scatter<<<nblk_scatter, 256, 0, stream>>>((const float4*)bufA, src, dst, isd, bufB, E);
        gemm_nt<64, 128, 16, 4, 8, true>
            <<<dim3(mtiles, 1), 256, 0, stream>>>(bufB, W2, bufA, N_NODES, F_HID, F_HID);
        k_agg_init<<<nblk_feat, 256, 0, stream>>>((const float4*)bufA, isd, (float4*)bufB);
        k_scatter<<<nblk_scatter, 256, 0, stream>>>((const float4*)bufA, src, dst, isd, bufB, E);
        gemm_lin<<<(N_NODES + 15) / 16, 256, 0, stream>>>(bufB, Wlin, out, N_NODES);
    }
}